// Round 5
// baseline (753.255 us; speedup 1.0000x reference)
//
#include <hip/hip_runtime.h>

typedef __bf16 bf16_t;
typedef bf16_t bf16x8 __attribute__((ext_vector_type(8)));
typedef float f32x4 __attribute__((ext_vector_type(4)));

#define HIDDEN 2048
#define SEQ 2048
#define BATCH 2
#define NHEADS 16
#define HDIM 128
#define MTOT (BATCH*SEQ)
#define SCALE 0.088388347648318447f
#define C1EXP2 0.12753102158508967f   /* SCALE * log2(e) */
#define LOG2E  1.4426950408889634f

// device exp2 without touching libm names (math.h macro collision on this toolchain)
__device__ __forceinline__ float dev_exp2(float x) { return __builtin_amdgcn_exp2f(x); }

// ---- async global->LDS (wave-uniform LDS base + lane*16, per m97) ----
typedef __attribute__((address_space(1))) const void gvoid_t;
typedef __attribute__((address_space(3))) void svoid_t;
__device__ __forceinline__ void async_copy16(const bf16_t* g, bf16_t* l) {
  __builtin_amdgcn_global_load_lds((gvoid_t*)g, (svoid_t*)l, 16, 0, 0);
}

// ---- fused fp32 -> bf16 cast for x + 4 weights (one dispatch) ----
__global__ void cvt_all(const float* __restrict__ x,  const float* __restrict__ wq,
                        const float* __restrict__ wk, const float* __restrict__ wv,
                        const float* __restrict__ wo,
                        bf16_t* __restrict__ xb, bf16_t* __restrict__ wqkb,
                        bf16_t* __restrict__ wvb, bf16_t* __restrict__ wob) {
  const size_t HH = (size_t)HIDDEN * HIDDEN;
  const float* src; bf16_t* dst;
  switch (blockIdx.y) {
    case 0:  src = x;        dst = xb;        break;
    case 1:  src = x + HH;   dst = xb + HH;   break;
    case 2:  src = wq;       dst = wqkb;      break;
    case 3:  src = wk;       dst = wqkb + HH; break;
    case 4:  src = wv;       dst = wvb;       break;
    default: src = wo;       dst = wob;       break;
  }
  int i = blockIdx.x * 256 + threadIdx.x;     // HH/4 float4s per region
  float4 v = reinterpret_cast<const float4*>(src)[i];
  union { bf16_t h[4]; uint2 u; } t;
  t.h[0] = (bf16_t)v.x; t.h[1] = (bf16_t)v.y; t.h[2] = (bf16_t)v.z; t.h[3] = (bf16_t)v.w;
  reinterpret_cast<uint2*>(dst)[i] = t.u;
}

__global__ void pack_bias2(const float* __restrict__ a, const float* __restrict__ b2,
                           float* __restrict__ out) {
  int i = blockIdx.x * 256 + threadIdx.x;      // 0..4095
  out[i] = (i < HIDDEN) ? a[i] : b2[i - HIDDEN];
}

// ---- GEMM: Y[i][j] = sum_k A[i][k]*Bt[j][k] + bias  (both operands K-major) ----
// 128x128 tile, BK=32, 4 waves in 2x2, 16x16x32 bf16 MFMA. m97 structure.
template<bool OUT_BF16, bool ROW_BIAS>
__global__ __launch_bounds__(256, 2)
void gemm_bt(const bf16_t* __restrict__ A, const bf16_t* __restrict__ Bt,
             const float* __restrict__ bias, void* __restrict__ Yv,
             int M, int N, int K, int ldY) {
  __shared__ __align__(16) bf16_t As[128 * 32];
  __shared__ __align__(16) bf16_t Bs[128 * 32];
  const int tid  = threadIdx.x;
  const int lane = tid & 63;
  const int wv   = tid >> 6;
  const int wr   = wv >> 1, wc = wv & 1;
  const int lr   = lane & 15, quad = lane >> 4;
  const int n0   = blockIdx.x * 128;
  const int m0   = blockIdx.y * 128;

  f32x4 acc[4][4] = {};

  const int srow = wv * 16 + (lane >> 2);      // 0..63
  const int scol = (lane & 3) * 8;
  const bf16_t* gA = A  + (size_t)(m0 + srow) * K + scol;
  const bf16_t* gB = Bt + (size_t)(n0 + srow) * K + scol;
  bf16_t* lA = &As[wv * 16 * 32];              // wave-uniform LDS base
  bf16_t* lB = &Bs[wv * 16 * 32];
  const size_t step64 = (size_t)64 * K;

  for (int kt = 0; kt < K; kt += 32) {
    __syncthreads();                           // prior ds_reads complete
    async_copy16(gA,          lA);
    async_copy16(gA + step64, lA + 64 * 32);
    async_copy16(gB,          lB);
    async_copy16(gB + step64, lB + 64 * 32);
    gA += 32; gB += 32;
    __syncthreads();                           // drains vmcnt -> tiles visible
    bf16x8 af[4], bfr[4];
#pragma unroll
    for (int mi = 0; mi < 4; ++mi)
      af[mi] = *(const bf16x8*)&As[(wr * 64 + mi * 16 + lr) * 32 + quad * 8];
#pragma unroll
    for (int ni = 0; ni < 4; ++ni)
      bfr[ni] = *(const bf16x8*)&Bs[(wc * 64 + ni * 16 + lr) * 32 + quad * 8];
#pragma unroll
    for (int mi = 0; mi < 4; ++mi)
#pragma unroll
      for (int ni = 0; ni < 4; ++ni)
        acc[mi][ni] = __builtin_amdgcn_mfma_f32_16x16x32_bf16(af[mi], bfr[ni], acc[mi][ni], 0, 0, 0);
  }

  float bcol[4];
  if (!ROW_BIAS) {
#pragma unroll
    for (int ni = 0; ni < 4; ++ni) bcol[ni] = bias[n0 + wc * 64 + ni * 16 + lr];
  }
#pragma unroll
  for (int mi = 0; mi < 4; ++mi) {
#pragma unroll
    for (int r = 0; r < 4; ++r) {
      int row = m0 + wr * 64 + mi * 16 + quad * 4 + r;
      float brow = ROW_BIAS ? bias[row] : 0.0f;
      size_t base = (size_t)row * ldY + n0 + wc * 64;
#pragma unroll
      for (int ni = 0; ni < 4; ++ni) {
        float y = acc[mi][ni][r] + (ROW_BIAS ? brow : bcol[ni]);
        int col = ni * 16 + lr;
        if (OUT_BF16) ((bf16_t*)Yv)[base + col] = (bf16_t)y;
        else          ((float*)Yv)[base + col]  = y;
      }
    }
  }
}

// ---- Flash attention v4 ----
// BQ=64 (wave owns 16 q rows), grid 1024, LDS 40 KB -> 4 blocks/CU.
// Register-buffered K/V software pipeline: prefetch next tile into VGPRs
// during compute; barriers bracket only the fast LDS writes, so the vmcnt
// wait lands on loads issued a full iteration earlier (drain stall gone).
// XOR chunk swizzle applied at the ds_write side (read side as v3, <=2-way,
// measured 0 conflicts). No online softmax (scores bounded); exp2 via
// __builtin_amdgcn_exp2f with pre-folded constants. P wave-private.
#define BQ 64
#define BKV 64
#define LDQK 4096

__global__ __launch_bounds__(256, 4)
void attn_kernel(const bf16_t* __restrict__ QK, const bf16_t* __restrict__ Vt,
                 const float* __restrict__ mask, bf16_t* __restrict__ O) {
  __shared__ __align__(16) bf16_t Ks[BKV * 128];   // 16384 B, swizzle key row&15
  __shared__ __align__(16) bf16_t Vs[HDIM * BKV];  // 16384 B, swizzle key d&7
  __shared__ __align__(16) bf16_t Ps[BQ * BKV];    //  8192 B, swizzle key row&7

  const int tid  = threadIdx.x;
  const int lane = tid & 63;
  const int wv   = tid >> 6;                       // wave owns q rows [wv*16, wv*16+16)
  const int lr   = lane & 15, quad = lane >> 4;
  const int q0   = blockIdx.x * BQ;
  const int bh   = blockIdx.y;
  const int b    = bh >> 4, h = bh & 15;

  const bf16_t* Qg = QK + (size_t)(b * SEQ + q0) * LDQK + h * HDIM;
  const bf16_t* Kg = QK + (size_t)(b * SEQ) * LDQK + HIDDEN + h * HDIM;
  const bf16_t* Vg = Vt + (size_t)(h * HDIM) * MTOT + b * SEQ;
  const float*  mb = mask + b * SEQ;

  // Q fragments straight from global (one-time; L2/L3-served)
  bf16x8 qf[4];
#pragma unroll
  for (int dk = 0; dk < 4; ++dk)
    qf[dk] = *(const bf16x8*)(Qg + (size_t)(wv * 16 + lr) * LDQK + dk * 32 + quad * 8);

  // staging coords: K 64x128 (4 rows of 16 chunks / wave / call),
  //                 V 128x64 (8 rows of 8 chunks / wave / call)
  const int krl = lane >> 4, kcs = lane & 15;      // K row-in-group, chunk
  const int vrl = lane >> 3, vcs = lane & 7;       // V row-in-group, chunk
  // loop-invariant LDS write addresses (swizzle baked in)
  int lKa[4], lVa[4];
  const bf16_t* kgp[4];
  const bf16_t* vgp[4];
#pragma unroll
  for (int i = 0; i < 4; ++i) {
    int row = wv * 16 + i * 4 + krl;               // 0..63
    lKa[i] = row * 128 + ((kcs ^ (row & 15)) * 8);
    kgp[i] = Kg + (size_t)row * LDQK + kcs * 8;    // linear global chunk
    int d = wv * 32 + i * 8 + vrl;                 // 0..127
    lVa[i] = d * BKV + ((vcs ^ (d & 7)) * 8);
    vgp[i] = Vg + (size_t)d * MTOT + vcs * 8;
  }

  // preload tile 0 into registers
  uint4 kreg[4], vreg[4];
#pragma unroll
  for (int i = 0; i < 4; ++i) {
    kreg[i] = *(const uint4*)(kgp[i]);
    vreg[i] = *(const uint4*)(vgp[i]);
  }

  float l_st[4] = {0.0f, 0.0f, 0.0f, 0.0f};
  f32x4 oacc[8] = {};

  for (int kt = 0; kt < SEQ; kt += BKV) {
    __syncthreads();   // all waves done reading prior K/V tiles
#pragma unroll
    for (int i = 0; i < 4; ++i) *(uint4*)&Ks[lKa[i]] = kreg[i];
#pragma unroll
    for (int i = 0; i < 4; ++i) *(uint4*)&Vs[lVa[i]] = vreg[i];
    __syncthreads();   // tiles visible

    // prefetch next tile into registers (in flight during all compute below)
    if (kt + BKV < SEQ) {
#pragma unroll
      for (int i = 0; i < 4; ++i) {
        kreg[i] = *(const uint4*)(kgp[i] + (size_t)(kt + BKV) * LDQK);
        vreg[i] = *(const uint4*)(vgp[i] + (kt + BKV));
      }
    }

    float mk[4];
#pragma unroll
    for (int ni = 0; ni < 4; ++ni) mk[ni] = mb[kt + ni * 16 + lr] * LOG2E;

    // S = Q K^T  (per wave: [16 q][64 k])
    f32x4 sacc[4] = {};
#pragma unroll
    for (int dk = 0; dk < 4; ++dk) {
      bf16x8 kf[4];
#pragma unroll
      for (int ni = 0; ni < 4; ++ni)
        kf[ni] = *(const bf16x8*)&Ks[(ni * 16 + lr) * 128 + (((dk * 4 + quad) ^ lr) * 8)];
#pragma unroll
      for (int ni = 0; ni < 4; ++ni)
        sacc[ni] = __builtin_amdgcn_mfma_f32_16x16x32_bf16(qf[dk], kf[ni], sacc[ni], 0, 0, 0);
    }

    // unnormalized P = exp2(S*C1 + mask*log2e); C-layout row = quad*4+r, col = lr
#pragma unroll
    for (int r = 0; r < 4; ++r) {
      float p0 = dev_exp2(fmaf(sacc[0][r], C1EXP2, mk[0]));
      float p1 = dev_exp2(fmaf(sacc[1][r], C1EXP2, mk[1]));
      float p2 = dev_exp2(fmaf(sacc[2][r], C1EXP2, mk[2]));
      float p3 = dev_exp2(fmaf(sacc[3][r], C1EXP2, mk[3]));
      int pr = wv * 16 + quad * 4 + r;
      int key = pr & 7;
      Ps[pr * BKV + (((0 + (lr >> 3)) ^ key) * 8) + (lr & 7)] = (bf16_t)p0;
      Ps[pr * BKV + (((2 + (lr >> 3)) ^ key) * 8) + (lr & 7)] = (bf16_t)p1;
      Ps[pr * BKV + (((4 + (lr >> 3)) ^ key) * 8) + (lr & 7)] = (bf16_t)p2;
      Ps[pr * BKV + (((6 + (lr >> 3)) ^ key) * 8) + (lr & 7)] = (bf16_t)p3;
      l_st[r] += (p0 + p1) + (p2 + p3);
    }
    // P wave-private -> no barrier

    // O += P V   (per wave: [16 q][128 d])
#pragma unroll
    for (int ki = 0; ki < 2; ++ki) {
      bf16x8 pf = *(const bf16x8*)&Ps[(wv * 16 + lr) * BKV + (((ki * 4 + quad) ^ (lr & 7)) * 8)];
#pragma unroll
      for (int di = 0; di < 8; ++di) {
        bf16x8 vf = *(const bf16x8*)&Vs[(di * 16 + lr) * BKV + (((ki * 4 + quad) ^ (lr & 7)) * 8)];
        oacc[di] = __builtin_amdgcn_mfma_f32_16x16x32_bf16(pf, vf, oacc[di], 0, 0, 0);
      }
    }
  }

  // epilogue: reduce l across the 16 lr-lanes, O /= l, write ctx bf16
  bf16_t* Ob = O + (size_t)(b * SEQ + q0) * HIDDEN + h * HDIM;
#pragma unroll
  for (int r = 0; r < 4; ++r) {
    float s = l_st[r];
    s += __shfl_xor(s, 1);
    s += __shfl_xor(s, 2);
    s += __shfl_xor(s, 4);
    s += __shfl_xor(s, 8);
    float inv = 1.0f / s;
    size_t rowoff = (size_t)(wv * 16 + quad * 4 + r) * HIDDEN;
#pragma unroll
    for (int di = 0; di < 8; ++di)
      Ob[rowoff + di * 16 + lr] = (bf16_t)(oacc[di][r] * inv);
  }
}

extern "C" void kernel_launch(void* const* d_in, const int* in_sizes, int n_in,
                              void* d_out, int out_size, void* d_ws, size_t ws_size,
                              hipStream_t stream) {
  const float* x   = (const float*)d_in[0];
  const float* msk = (const float*)d_in[1];
  const float* Wq  = (const float*)d_in[2];
  const float* bq  = (const float*)d_in[3];
  const float* Wk  = (const float*)d_in[4];
  const float* bk  = (const float*)d_in[5];
  const float* Wv  = (const float*)d_in[6];
  const float* bv  = (const float*)d_in[7];
  const float* Wo  = (const float*)d_in[8];
  const float* bo  = (const float*)d_in[9];
  float* out = (float*)d_out;

  // workspace layout (bf16 elems), ~101 MB total
  bf16_t* Xb   = (bf16_t*)d_ws;
  bf16_t* Wqkb = Xb   + (size_t)MTOT * HIDDEN;            // Wq|Wk stacked [4096][2048]
  bf16_t* Wvb  = Wqkb + (size_t)2 * HIDDEN * HIDDEN;
  bf16_t* Wob  = Wvb  + (size_t)HIDDEN * HIDDEN;
  bf16_t* QKo  = Wob  + (size_t)HIDDEN * HIDDEN;          // [4096][4096]
  bf16_t* Vto  = QKo  + (size_t)MTOT * 2 * HIDDEN;        // [2048][4096]
  float*  bqk  = (float*)(Vto + (size_t)HIDDEN * MTOT);   // [4096] fp32
  bf16_t* Cb   = Xb;  // ctx aliases Xb (Xb dead after Vt GEMM)

  // fused casts: 6 regions x (HH/4 float4 / 256) blocks
  cvt_all<<<dim3(HIDDEN * HIDDEN / 4 / 256, 6), 256, 0, stream>>>(
      x, Wq, Wk, Wv, Wo, Xb, Wqkb, Wvb, Wob);
  pack_bias2<<<2 * HIDDEN / 256, 256, 0, stream>>>(bq, bk, bqk);

  // QK projection: [4096,2048] x [4096,2048]^T -> [4096][4096]
  gemm_bt<true, false><<<dim3(32, 32), 256, 0, stream>>>(Xb, Wqkb, bqk, QKo,
                                                         MTOT, 2 * HIDDEN, HIDDEN, 2 * HIDDEN);
  // V^T projection (operands swapped): [2048,2048] x [4096,2048]^T -> [2048][4096], row bias
  gemm_bt<true, true><<<dim3(32, 16), 256, 0, stream>>>(Wvb, Xb, bv, Vto,
                                                        HIDDEN, MTOT, HIDDEN, MTOT);
  // attention -> ctx bf16 [4096][2048]
  attn_kernel<<<dim3(SEQ / BQ, BATCH * NHEADS), 256, 0, stream>>>(QKo, Vto, msk, Cb);
  // output projection -> fp32 out
  gemm_bt<false, false><<<dim3(16, 32), 256, 0, stream>>>(Cb, Wob, bo, out,
                                                          MTOT, HIDDEN, HIDDEN, HIDDEN);
}

// Round 6
// 419.241 us; speedup vs baseline: 1.7967x; 1.7967x over previous
//
#include <hip/hip_runtime.h>

typedef __bf16 bf16_t;
typedef bf16_t bf16x8 __attribute__((ext_vector_type(8)));
typedef float f32x4 __attribute__((ext_vector_type(4)));

#define HIDDEN 2048
#define SEQ 2048
#define BATCH 2
#define NHEADS 16
#define HDIM 128
#define MTOT (BATCH*SEQ)
#define SCALE 0.088388347648318447f
#define C1EXP2 0.12753102158508967f   /* SCALE * log2(e) */
#define LOG2E  1.4426950408889634f

// device exp2 without touching libm names (math.h macro collision on this toolchain)
__device__ __forceinline__ float dev_exp2(float x) { return __builtin_amdgcn_exp2f(x); }

// ---- async global->LDS (wave-uniform LDS base + lane*16, per m97) ----
typedef __attribute__((address_space(1))) const void gvoid_t;
typedef __attribute__((address_space(3))) void svoid_t;
__device__ __forceinline__ void async_copy16(const bf16_t* g, bf16_t* l) {
  __builtin_amdgcn_global_load_lds((gvoid_t*)g, (svoid_t*)l, 16, 0, 0);
}

// ---- fused fp32 -> bf16 cast for x + 4 weights (one dispatch) ----
__global__ void cvt_all(const float* __restrict__ x,  const float* __restrict__ wq,
                        const float* __restrict__ wk, const float* __restrict__ wv,
                        const float* __restrict__ wo,
                        bf16_t* __restrict__ xb, bf16_t* __restrict__ wqkb,
                        bf16_t* __restrict__ wvb, bf16_t* __restrict__ wob) {
  const size_t HH = (size_t)HIDDEN * HIDDEN;
  const float* src; bf16_t* dst;
  switch (blockIdx.y) {
    case 0:  src = x;        dst = xb;        break;
    case 1:  src = x + HH;   dst = xb + HH;   break;
    case 2:  src = wq;       dst = wqkb;      break;
    case 3:  src = wk;       dst = wqkb + HH; break;
    case 4:  src = wv;       dst = wvb;       break;
    default: src = wo;       dst = wob;       break;
  }
  int i = blockIdx.x * 256 + threadIdx.x;     // HH/4 float4s per region
  float4 v = reinterpret_cast<const float4*>(src)[i];
  union { bf16_t h[4]; uint2 u; } t;
  t.h[0] = (bf16_t)v.x; t.h[1] = (bf16_t)v.y; t.h[2] = (bf16_t)v.z; t.h[3] = (bf16_t)v.w;
  reinterpret_cast<uint2*>(dst)[i] = t.u;
}

__global__ void pack_bias2(const float* __restrict__ a, const float* __restrict__ b2,
                           float* __restrict__ out) {
  int i = blockIdx.x * 256 + threadIdx.x;      // 0..4095
  out[i] = (i < HIDDEN) ? a[i] : b2[i - HIDDEN];
}

// ---- GEMM: Y[i][j] = sum_k A[i][k]*Bt[j][k] + bias  (both operands K-major) ----
// 128x128 tile, BK=32, 4 waves in 2x2, 16x16x32 bf16 MFMA. m97 structure.
template<bool OUT_BF16, bool ROW_BIAS>
__global__ __launch_bounds__(256, 2)
void gemm_bt(const bf16_t* __restrict__ A, const bf16_t* __restrict__ Bt,
             const float* __restrict__ bias, void* __restrict__ Yv,
             int M, int N, int K, int ldY) {
  __shared__ __align__(16) bf16_t As[128 * 32];
  __shared__ __align__(16) bf16_t Bs[128 * 32];
  const int tid  = threadIdx.x;
  const int lane = tid & 63;
  const int wv   = tid >> 6;
  const int wr   = wv >> 1, wc = wv & 1;
  const int lr   = lane & 15, quad = lane >> 4;
  const int n0   = blockIdx.x * 128;
  const int m0   = blockIdx.y * 128;

  f32x4 acc[4][4] = {};

  const int srow = wv * 16 + (lane >> 2);      // 0..63
  const int scol = (lane & 3) * 8;
  const bf16_t* gA = A  + (size_t)(m0 + srow) * K + scol;
  const bf16_t* gB = Bt + (size_t)(n0 + srow) * K + scol;
  bf16_t* lA = &As[wv * 16 * 32];              // wave-uniform LDS base
  bf16_t* lB = &Bs[wv * 16 * 32];
  const size_t step64 = (size_t)64 * K;

  for (int kt = 0; kt < K; kt += 32) {
    __syncthreads();                           // prior ds_reads complete
    async_copy16(gA,          lA);
    async_copy16(gA + step64, lA + 64 * 32);
    async_copy16(gB,          lB);
    async_copy16(gB + step64, lB + 64 * 32);
    gA += 32; gB += 32;
    __syncthreads();                           // drains vmcnt -> tiles visible
    bf16x8 af[4], bfr[4];
#pragma unroll
    for (int mi = 0; mi < 4; ++mi)
      af[mi] = *(const bf16x8*)&As[(wr * 64 + mi * 16 + lr) * 32 + quad * 8];
#pragma unroll
    for (int ni = 0; ni < 4; ++ni)
      bfr[ni] = *(const bf16x8*)&Bs[(wc * 64 + ni * 16 + lr) * 32 + quad * 8];
#pragma unroll
    for (int mi = 0; mi < 4; ++mi)
#pragma unroll
      for (int ni = 0; ni < 4; ++ni)
        acc[mi][ni] = __builtin_amdgcn_mfma_f32_16x16x32_bf16(af[mi], bfr[ni], acc[mi][ni], 0, 0, 0);
  }

  float bcol[4];
  if (!ROW_BIAS) {
#pragma unroll
    for (int ni = 0; ni < 4; ++ni) bcol[ni] = bias[n0 + wc * 64 + ni * 16 + lr];
  }
#pragma unroll
  for (int mi = 0; mi < 4; ++mi) {
#pragma unroll
    for (int r = 0; r < 4; ++r) {
      int row = m0 + wr * 64 + mi * 16 + quad * 4 + r;
      float brow = ROW_BIAS ? bias[row] : 0.0f;
      size_t base = (size_t)row * ldY + n0 + wc * 64;
#pragma unroll
      for (int ni = 0; ni < 4; ++ni) {
        float y = acc[mi][ni][r] + (ROW_BIAS ? brow : bcol[ni]);
        int col = ni * 16 + lr;
        if (OUT_BF16) ((bf16_t*)Yv)[base + col] = (bf16_t)y;
        else          ((float*)Yv)[base + col]  = y;
      }
    }
  }
}

// ---- Flash attention v5 ----
// LDS-BW-bound fix: M=32 q-rows/wave (BQ=128, 4 waves) halves K/V fragment
// re-reads per MFMA (16/M scaling): 4.5 GB -> 2.36 GB total ds_read traffic.
// Double-buffered K/V staged via global_load_lds (zero staging VGPRs -> no
// spills, the R2/R5 failure mode); next tile's DMA issued right after the
// single per-iter barrier so its vmcnt drain (at the NEXT barrier) waits on
// loads that had the whole compute section in flight. LDS 80 KB -> 2
// blocks/CU, grid 512 = exactly 2/CU. XOR chunk swizzle baked into the
// global source column (LDS dst stays linear for global_load_lds); all
// ds_read_b128 <=2-way (measured 0 conflicts). No online softmax (scores
// bounded). P single-buffer, wave-private.
#define BQ 128
#define BKV 64
#define LDQK 4096

__global__ __launch_bounds__(256, 2)
void attn_kernel(const bf16_t* __restrict__ QK, const bf16_t* __restrict__ Vt,
                 const float* __restrict__ mask, bf16_t* __restrict__ O) {
  __shared__ __align__(16) bf16_t Ks[2][BKV * 128];   // 2 x 16 KB
  __shared__ __align__(16) bf16_t Vs[2][HDIM * BKV];  // 2 x 16 KB
  __shared__ __align__(16) bf16_t Ps[BQ * BKV];       // 16 KB   (total 80 KB)

  const int tid  = threadIdx.x;
  const int lane = tid & 63;
  const int wv   = tid >> 6;                       // wave owns q rows [wv*32, wv*32+32)
  const int lr   = lane & 15, quad = lane >> 4;
  const int q0   = blockIdx.x * BQ;
  const int bh   = blockIdx.y;
  const int b    = bh >> 4, h = bh & 15;

  const bf16_t* Qg = QK + (size_t)(b * SEQ + q0) * LDQK + h * HDIM;
  const bf16_t* Kg = QK + (size_t)(b * SEQ) * LDQK + HIDDEN + h * HDIM;
  const bf16_t* Vg = Vt + (size_t)(h * HDIM) * MTOT + b * SEQ;
  const float*  mb = mask + b * SEQ;

  // Q fragments straight from global (one-time; L2/L3-served). 32 VGPRs.
  bf16x8 qf[2][4];
#pragma unroll
  for (int mi = 0; mi < 2; ++mi)
#pragma unroll
    for (int dk = 0; dk < 4; ++dk)
      qf[mi][dk] = *(const bf16x8*)(Qg + (size_t)(wv * 32 + mi * 16 + lr) * LDQK + dk * 32 + quad * 8);

  // staging geometry (wave-cooperative global_load_lds, swizzle on src column)
  // K tile 64x128: call i covers rows i*16..i*16+15; this wave rows i*16+wv*4+(lane>>4)
  // V tile 128x64: call i covers rows i*32..i*32+31; this wave rows i*32+wv*8+(lane>>3)
  const int kcs = lane & 15;                       // K chunk (16B units)
  const int vcs = lane & 7;                        // V chunk
  const bf16_t* kgp[4]; const bf16_t* vgp[4];
  int lKo[4], lVo[4];
#pragma unroll
  for (int i = 0; i < 4; ++i) {
    int kr = i * 16 + wv * 4 + (lane >> 4);        // 0..63
    kgp[i] = Kg + (size_t)kr * LDQK + ((kcs ^ (kr & 15)) * 8);
    lKo[i] = (i * 16 + wv * 4) * 128;              // wave-uniform; HW adds lane*16B
    int vr = i * 32 + wv * 8 + (lane >> 3);        // 0..127
    vgp[i] = Vg + (size_t)vr * MTOT + ((vcs ^ (vr & 7)) * 8);
    lVo[i] = (i * 32 + wv * 8) * 64;
  }

  float l_st[2][4] = {};
  f32x4 oacc[2][8] = {};

  // preload tile 0 into buffer 0
#pragma unroll
  for (int i = 0; i < 4; ++i) async_copy16(kgp[i], &Ks[0][lKo[i]]);
#pragma unroll
  for (int i = 0; i < 4; ++i) async_copy16(vgp[i], &Vs[0][lVo[i]]);

  for (int kt = 0; kt < SEQ; kt += 2 * BKV) {
#pragma unroll
    for (int half = 0; half < 2; ++half) {
      const int cur  = half;                       // compile-time after unroll
      const int kcur = kt + half * BKV;
      __syncthreads();  // drains own DMA (buf cur visible) + all waves' reads of buf cur done
      const int knext = kcur + BKV;
      if (knext < SEQ) {                           // uniform branch
#pragma unroll
        for (int i = 0; i < 4; ++i) async_copy16(kgp[i] + (size_t)knext * LDQK, &Ks[cur ^ 1][lKo[i]]);
#pragma unroll
        for (int i = 0; i < 4; ++i) async_copy16(vgp[i] + knext, &Vs[cur ^ 1][lVo[i]]);
      }

      float mk[4];
#pragma unroll
      for (int ni = 0; ni < 4; ++ni) mk[ni] = mb[kcur + ni * 16 + lr] * LOG2E;

      // S = Q K^T  (per wave: [32 q][64 k])
      f32x4 sacc[2][4] = {};
#pragma unroll
      for (int dk = 0; dk < 4; ++dk) {
        bf16x8 kf[4];
#pragma unroll
        for (int ni = 0; ni < 4; ++ni)
          kf[ni] = *(const bf16x8*)&Ks[cur][(ni * 16 + lr) * 128 + (((dk * 4 + quad) ^ lr) * 8)];
#pragma unroll
        for (int mi = 0; mi < 2; ++mi)
#pragma unroll
          for (int ni = 0; ni < 4; ++ni)
            sacc[mi][ni] = __builtin_amdgcn_mfma_f32_16x16x32_bf16(qf[mi][dk], kf[ni], sacc[mi][ni], 0, 0, 0);
      }

      // unnormalized P = exp2(S*C1 + mask*log2e); C-layout row = quad*4+r, col = lr
#pragma unroll
      for (int mi = 0; mi < 2; ++mi) {
#pragma unroll
        for (int r = 0; r < 4; ++r) {
          float p0 = dev_exp2(fmaf(sacc[mi][0][r], C1EXP2, mk[0]));
          float p1 = dev_exp2(fmaf(sacc[mi][1][r], C1EXP2, mk[1]));
          float p2 = dev_exp2(fmaf(sacc[mi][2][r], C1EXP2, mk[2]));
          float p3 = dev_exp2(fmaf(sacc[mi][3][r], C1EXP2, mk[3]));
          int pr = wv * 32 + mi * 16 + quad * 4 + r;
          int key = pr & 7;
          Ps[pr * BKV + (((0 + (lr >> 3)) ^ key) * 8) + (lr & 7)] = (bf16_t)p0;
          Ps[pr * BKV + (((2 + (lr >> 3)) ^ key) * 8) + (lr & 7)] = (bf16_t)p1;
          Ps[pr * BKV + (((4 + (lr >> 3)) ^ key) * 8) + (lr & 7)] = (bf16_t)p2;
          Ps[pr * BKV + (((6 + (lr >> 3)) ^ key) * 8) + (lr & 7)] = (bf16_t)p3;
          l_st[mi][r] += (p0 + p1) + (p2 + p3);
        }
      }
      // P wave-private -> no barrier

      // O += P V   (per wave: [32 q][128 d])
#pragma unroll
      for (int ki = 0; ki < 2; ++ki) {
        bf16x8 pf[2];
#pragma unroll
        for (int mi = 0; mi < 2; ++mi)
          pf[mi] = *(const bf16x8*)&Ps[(wv * 32 + mi * 16 + lr) * BKV + (((ki * 4 + quad) ^ (lr & 7)) * 8)];
#pragma unroll
        for (int di = 0; di < 8; ++di) {
          bf16x8 vf = *(const bf16x8*)&Vs[cur][(di * 16 + lr) * BKV + (((ki * 4 + quad) ^ (lr & 7)) * 8)];
#pragma unroll
          for (int mi = 0; mi < 2; ++mi)
            oacc[mi][di] = __builtin_amdgcn_mfma_f32_16x16x32_bf16(pf[mi], vf, oacc[mi][di], 0, 0, 0);
        }
      }
    }
  }

  // epilogue: reduce l across the 16 lr-lanes, O /= l, write ctx bf16
  bf16_t* Ob = O + (size_t)(b * SEQ + q0) * HIDDEN + h * HDIM;
#pragma unroll
  for (int mi = 0; mi < 2; ++mi) {
#pragma unroll
    for (int r = 0; r < 4; ++r) {
      float s = l_st[mi][r];
      s += __shfl_xor(s, 1);
      s += __shfl_xor(s, 2);
      s += __shfl_xor(s, 4);
      s += __shfl_xor(s, 8);
      float inv = 1.0f / s;
      size_t rowoff = (size_t)(wv * 32 + mi * 16 + quad * 4 + r) * HIDDEN;
#pragma unroll
      for (int di = 0; di < 8; ++di)
        Ob[rowoff + di * 16 + lr] = (bf16_t)(oacc[mi][di][r] * inv);
    }
  }
}

extern "C" void kernel_launch(void* const* d_in, const int* in_sizes, int n_in,
                              void* d_out, int out_size, void* d_ws, size_t ws_size,
                              hipStream_t stream) {
  const float* x   = (const float*)d_in[0];
  const float* msk = (const float*)d_in[1];
  const float* Wq  = (const float*)d_in[2];
  const float* bq  = (const float*)d_in[3];
  const float* Wk  = (const float*)d_in[4];
  const float* bk  = (const float*)d_in[5];
  const float* Wv  = (const float*)d_in[6];
  const float* bv  = (const float*)d_in[7];
  const float* Wo  = (const float*)d_in[8];
  const float* bo  = (const float*)d_in[9];
  float* out = (float*)d_out;

  // workspace layout (bf16 elems), ~101 MB total
  bf16_t* Xb   = (bf16_t*)d_ws;
  bf16_t* Wqkb = Xb   + (size_t)MTOT * HIDDEN;            // Wq|Wk stacked [4096][2048]
  bf16_t* Wvb  = Wqkb + (size_t)2 * HIDDEN * HIDDEN;
  bf16_t* Wob  = Wvb  + (size_t)HIDDEN * HIDDEN;
  bf16_t* QKo  = Wob  + (size_t)HIDDEN * HIDDEN;          // [4096][4096]
  bf16_t* Vto  = QKo  + (size_t)MTOT * 2 * HIDDEN;        // [2048][4096]
  float*  bqk  = (float*)(Vto + (size_t)HIDDEN * MTOT);   // [4096] fp32
  bf16_t* Cb   = Xb;  // ctx aliases Xb (Xb dead after Vt GEMM)

  // fused casts: 6 regions x (HH/4 float4 / 256) blocks
  cvt_all<<<dim3(HIDDEN * HIDDEN / 4 / 256, 6), 256, 0, stream>>>(
      x, Wq, Wk, Wv, Wo, Xb, Wqkb, Wvb, Wob);
  pack_bias2<<<2 * HIDDEN / 256, 256, 0, stream>>>(bq, bk, bqk);

  // QK projection: [4096,2048] x [4096,2048]^T -> [4096][4096]
  gemm_bt<true, false><<<dim3(32, 32), 256, 0, stream>>>(Xb, Wqkb, bqk, QKo,
                                                         MTOT, 2 * HIDDEN, HIDDEN, 2 * HIDDEN);
  // V^T projection (operands swapped): [2048,2048] x [4096,2048]^T -> [2048][4096], row bias
  gemm_bt<true, true><<<dim3(32, 16), 256, 0, stream>>>(Wvb, Xb, bv, Vto,
                                                        HIDDEN, MTOT, HIDDEN, MTOT);
  // attention -> ctx bf16 [4096][2048]
  attn_kernel<<<dim3(SEQ / BQ, BATCH * NHEADS), 256, 0, stream>>>(QKo, Vto, msk, Cb);
  // output projection -> fp32 out
  gemm_bt<false, false><<<dim3(16, 32), 256, 0, stream>>>(Cb, Wob, bo, out,
                                                          MTOT, HIDDEN, HIDDEN, HIDDEN);
}

// Round 7
// 414.967 us; speedup vs baseline: 1.8152x; 1.0103x over previous
//
#include <hip/hip_runtime.h>

typedef __bf16 bf16_t;
typedef bf16_t bf16x8 __attribute__((ext_vector_type(8)));
typedef float f32x4 __attribute__((ext_vector_type(4)));

#define HIDDEN 2048
#define SEQ 2048
#define BATCH 2
#define NHEADS 16
#define HDIM 128
#define MTOT (BATCH*SEQ)
#define SCALE 0.088388347648318447f
#define C1EXP2 0.12753102158508967f   /* SCALE * log2(e) */
#define LOG2E  1.4426950408889634f

// device exp2 without touching libm names (math.h macro collision on this toolchain)
__device__ __forceinline__ float dev_exp2(float x) { return __builtin_amdgcn_exp2f(x); }

// ---- async global->LDS (wave-uniform LDS base + lane*16, per m97) ----
typedef __attribute__((address_space(1))) const void gvoid_t;
typedef __attribute__((address_space(3))) void svoid_t;
__device__ __forceinline__ void async_copy16(const bf16_t* g, bf16_t* l) {
  __builtin_amdgcn_global_load_lds((gvoid_t*)g, (svoid_t*)l, 16, 0, 0);
}

// ---- fused fp32 -> bf16 cast for x + 4 weights (one dispatch) ----
__global__ void cvt_all(const float* __restrict__ x,  const float* __restrict__ wq,
                        const float* __restrict__ wk, const float* __restrict__ wv,
                        const float* __restrict__ wo,
                        bf16_t* __restrict__ xb, bf16_t* __restrict__ wqkb,
                        bf16_t* __restrict__ wvb, bf16_t* __restrict__ wob) {
  const size_t HH = (size_t)HIDDEN * HIDDEN;
  const float* src; bf16_t* dst;
  switch (blockIdx.y) {
    case 0:  src = x;        dst = xb;        break;
    case 1:  src = x + HH;   dst = xb + HH;   break;
    case 2:  src = wq;       dst = wqkb;      break;
    case 3:  src = wk;       dst = wqkb + HH; break;
    case 4:  src = wv;       dst = wvb;       break;
    default: src = wo;       dst = wob;       break;
  }
  int i = blockIdx.x * 256 + threadIdx.x;     // HH/4 float4s per region
  float4 v = reinterpret_cast<const float4*>(src)[i];
  union { bf16_t h[4]; uint2 u; } t;
  t.h[0] = (bf16_t)v.x; t.h[1] = (bf16_t)v.y; t.h[2] = (bf16_t)v.z; t.h[3] = (bf16_t)v.w;
  reinterpret_cast<uint2*>(dst)[i] = t.u;
}

__global__ void pack_bias2(const float* __restrict__ a, const float* __restrict__ b2,
                           float* __restrict__ out) {
  int i = blockIdx.x * 256 + threadIdx.x;      // 0..4095
  out[i] = (i < HIDDEN) ? a[i] : b2[i - HIDDEN];
}

// ---- GEMM: Y[i][j] = sum_k A[i][k]*Bt[j][k] + bias  (both operands K-major) ----
// 128x128 tile, BK=32, 4 waves in 2x2, 16x16x32 bf16 MFMA. m97 structure.
// launch_bounds (256,3): VGPR cap ~170 -> 3 blocks/CU (m97 precedent: 164 VGPR).
template<bool OUT_BF16, bool ROW_BIAS>
__global__ __launch_bounds__(256, 3)
void gemm_bt(const bf16_t* __restrict__ A, const bf16_t* __restrict__ Bt,
             const float* __restrict__ bias, void* __restrict__ Yv,
             int M, int N, int K, int ldY) {
  __shared__ __align__(16) bf16_t As[128 * 32];
  __shared__ __align__(16) bf16_t Bs[128 * 32];
  const int tid  = threadIdx.x;
  const int lane = tid & 63;
  const int wv   = tid >> 6;
  const int wr   = wv >> 1, wc = wv & 1;
  const int lr   = lane & 15, quad = lane >> 4;
  const int n0   = blockIdx.x * 128;
  const int m0   = blockIdx.y * 128;

  f32x4 acc[4][4] = {};

  const int srow = wv * 16 + (lane >> 2);      // 0..63
  const int scol = (lane & 3) * 8;
  const bf16_t* gA = A  + (size_t)(m0 + srow) * K + scol;
  const bf16_t* gB = Bt + (size_t)(n0 + srow) * K + scol;
  bf16_t* lA = &As[wv * 16 * 32];              // wave-uniform LDS base
  bf16_t* lB = &Bs[wv * 16 * 32];
  const size_t step64 = (size_t)64 * K;

  for (int kt = 0; kt < K; kt += 32) {
    __syncthreads();                           // prior ds_reads complete
    async_copy16(gA,          lA);
    async_copy16(gA + step64, lA + 64 * 32);
    async_copy16(gB,          lB);
    async_copy16(gB + step64, lB + 64 * 32);
    gA += 32; gB += 32;
    __syncthreads();                           // drains vmcnt -> tiles visible
    bf16x8 af[4], bfr[4];
#pragma unroll
    for (int mi = 0; mi < 4; ++mi)
      af[mi] = *(const bf16x8*)&As[(wr * 64 + mi * 16 + lr) * 32 + quad * 8];
#pragma unroll
    for (int ni = 0; ni < 4; ++ni)
      bfr[ni] = *(const bf16x8*)&Bs[(wc * 64 + ni * 16 + lr) * 32 + quad * 8];
#pragma unroll
    for (int mi = 0; mi < 4; ++mi)
#pragma unroll
      for (int ni = 0; ni < 4; ++ni)
        acc[mi][ni] = __builtin_amdgcn_mfma_f32_16x16x32_bf16(af[mi], bfr[ni], acc[mi][ni], 0, 0, 0);
  }

  float bcol[4];
  if (!ROW_BIAS) {
#pragma unroll
    for (int ni = 0; ni < 4; ++ni) bcol[ni] = bias[n0 + wc * 64 + ni * 16 + lr];
  }
#pragma unroll
  for (int mi = 0; mi < 4; ++mi) {
#pragma unroll
    for (int r = 0; r < 4; ++r) {
      int row = m0 + wr * 64 + mi * 16 + quad * 4 + r;
      float brow = ROW_BIAS ? bias[row] : 0.0f;
      size_t base = (size_t)row * ldY + n0 + wc * 64;
#pragma unroll
      for (int ni = 0; ni < 4; ++ni) {
        float y = acc[mi][ni][r] + (ROW_BIAS ? brow : bcol[ni]);
        int col = ni * 16 + lr;
        if (OUT_BF16) ((bf16_t*)Yv)[base + col] = (bf16_t)y;
        else          ((float*)Yv)[base + col]  = y;
      }
    }
  }
}

// ---- Flash attention v6 ----
// M=32 q-rows/wave (low LDS traffic) AND fine-grained occupancy: 128-thread
// blocks (2 waves), BQ=64 -> grid 1024. LDS single-buffered K(16K)+V(16K)+
// P(8K) = 40 KB -> 4 blocks/CU (exactly 160 KB). The per-iter vmcnt drain of
// the 2-barrier DMA loop is hidden by the 3 OTHER independent blocks on the
// CU (m114 wave-level overlap) -- R6's 2x4-wave layout could not do this.
// K/V staged via global_load_lds: zero staging VGPRs -> spill-proof (R2/R5
// lesson: register prefetch + AGPR accumulators blow the unified file).
// XOR chunk swizzle on the global source column; all ds_read_b128 <=2-way
// (measured 0 conflicts). No online softmax (scores bounded). P wave-private.
#define BQ 64
#define BKV 64
#define LDQK 4096

__global__ __launch_bounds__(128, 2)
void attn_kernel(const bf16_t* __restrict__ QK, const bf16_t* __restrict__ Vt,
                 const float* __restrict__ mask, bf16_t* __restrict__ O) {
  __shared__ __align__(16) bf16_t Ks[BKV * 128];   // 16 KB, swizzle key row&15
  __shared__ __align__(16) bf16_t Vs[HDIM * BKV];  // 16 KB, swizzle key d&7
  __shared__ __align__(16) bf16_t Ps[BQ * BKV];    //  8 KB, swizzle key row&7

  const int tid  = threadIdx.x;
  const int lane = tid & 63;
  const int wv   = tid >> 6;                       // wave owns q rows [wv*32, wv*32+32)
  const int lr   = lane & 15, quad = lane >> 4;
  const int q0   = blockIdx.x * BQ;
  const int bh   = blockIdx.y;
  const int b    = bh >> 4, h = bh & 15;

  const bf16_t* Qg = QK + (size_t)(b * SEQ + q0) * LDQK + h * HDIM;
  const bf16_t* Kg = QK + (size_t)(b * SEQ) * LDQK + HIDDEN + h * HDIM;
  const bf16_t* Vg = Vt + (size_t)(h * HDIM) * MTOT + b * SEQ;
  const float*  mb = mask + b * SEQ;

  // Q fragments straight from global (one-time; L2/L3-served). 32 VGPRs.
  bf16x8 qf[2][4];
#pragma unroll
  for (int mi = 0; mi < 2; ++mi)
#pragma unroll
    for (int dk = 0; dk < 4; ++dk)
      qf[mi][dk] = *(const bf16x8*)(Qg + (size_t)(wv * 32 + mi * 16 + lr) * LDQK + dk * 32 + quad * 8);

  // staging: K tile 64x128 = 16 calls (8/wave); V tile 128x64 = 16 calls (8/wave)
  const int kcs = lane & 15;                       // K chunk (16B units)
  const int vcs = lane & 7;                        // V chunk
  const bf16_t* kgp[8]; const bf16_t* vgp[8];
  int lKo[8], lVo[8];
#pragma unroll
  for (int i = 0; i < 8; ++i) {
    int kr = wv * 32 + i * 4 + (lane >> 4);        // 0..63
    kgp[i] = Kg + (size_t)kr * LDQK + ((kcs ^ (kr & 15)) * 8);
    lKo[i] = (wv * 32 + i * 4) * 128;              // wave-uniform; HW adds lane*16B
    int vr = wv * 64 + i * 8 + (lane >> 3);        // 0..127
    vgp[i] = Vg + (size_t)vr * MTOT + ((vcs ^ (vr & 7)) * 8);
    lVo[i] = (wv * 64 + i * 8) * 64;
  }

  float l_st[2][4] = {};
  f32x4 oacc[2][8] = {};

  for (int kt = 0; kt < SEQ; kt += BKV) {
    __syncthreads();   // all waves done reading prior K/V tiles
#pragma unroll
    for (int i = 0; i < 8; ++i) async_copy16(kgp[i] + (size_t)kt * LDQK, &Ks[lKo[i]]);
#pragma unroll
    for (int i = 0; i < 8; ++i) async_copy16(vgp[i] + kt, &Vs[lVo[i]]);
    __syncthreads();   // drains vmcnt -> tiles visible

    float mk[4];
#pragma unroll
    for (int ni = 0; ni < 4; ++ni) mk[ni] = mb[kt + ni * 16 + lr] * LOG2E;

    // S = Q K^T  (per wave: [32 q][64 k])
    f32x4 sacc[2][4] = {};
#pragma unroll
    for (int dk = 0; dk < 4; ++dk) {
      bf16x8 kf[4];
#pragma unroll
      for (int ni = 0; ni < 4; ++ni)
        kf[ni] = *(const bf16x8*)&Ks[(ni * 16 + lr) * 128 + (((dk * 4 + quad) ^ lr) * 8)];
#pragma unroll
      for (int mi = 0; mi < 2; ++mi)
#pragma unroll
        for (int ni = 0; ni < 4; ++ni)
          sacc[mi][ni] = __builtin_amdgcn_mfma_f32_16x16x32_bf16(qf[mi][dk], kf[ni], sacc[mi][ni], 0, 0, 0);
    }

    // unnormalized P = exp2(S*C1 + mask*log2e); C-layout row = quad*4+r, col = lr
#pragma unroll
    for (int mi = 0; mi < 2; ++mi) {
#pragma unroll
      for (int r = 0; r < 4; ++r) {
        float p0 = dev_exp2(fmaf(sacc[mi][0][r], C1EXP2, mk[0]));
        float p1 = dev_exp2(fmaf(sacc[mi][1][r], C1EXP2, mk[1]));
        float p2 = dev_exp2(fmaf(sacc[mi][2][r], C1EXP2, mk[2]));
        float p3 = dev_exp2(fmaf(sacc[mi][3][r], C1EXP2, mk[3]));
        int pr = wv * 32 + mi * 16 + quad * 4 + r;
        int key = pr & 7;
        Ps[pr * BKV + (((0 + (lr >> 3)) ^ key) * 8) + (lr & 7)] = (bf16_t)p0;
        Ps[pr * BKV + (((2 + (lr >> 3)) ^ key) * 8) + (lr & 7)] = (bf16_t)p1;
        Ps[pr * BKV + (((4 + (lr >> 3)) ^ key) * 8) + (lr & 7)] = (bf16_t)p2;
        Ps[pr * BKV + (((6 + (lr >> 3)) ^ key) * 8) + (lr & 7)] = (bf16_t)p3;
        l_st[mi][r] += (p0 + p1) + (p2 + p3);
      }
    }
    // P wave-private -> no barrier

    // O += P V   (per wave: [32 q][128 d])
#pragma unroll
    for (int ki = 0; ki < 2; ++ki) {
      bf16x8 pf[2];
#pragma unroll
      for (int mi = 0; mi < 2; ++mi)
        pf[mi] = *(const bf16x8*)&Ps[(wv * 32 + mi * 16 + lr) * BKV + (((ki * 4 + quad) ^ (lr & 7)) * 8)];
#pragma unroll
      for (int di = 0; di < 8; ++di) {
        bf16x8 vf = *(const bf16x8*)&Vs[(di * 16 + lr) * BKV + (((ki * 4 + quad) ^ (lr & 7)) * 8)];
#pragma unroll
        for (int mi = 0; mi < 2; ++mi)
          oacc[mi][di] = __builtin_amdgcn_mfma_f32_16x16x32_bf16(pf[mi], vf, oacc[mi][di], 0, 0, 0);
      }
    }
  }

  // epilogue: reduce l across the 16 lr-lanes, O /= l, write ctx bf16
  bf16_t* Ob = O + (size_t)(b * SEQ + q0) * HIDDEN + h * HDIM;
#pragma unroll
  for (int mi = 0; mi < 2; ++mi) {
#pragma unroll
    for (int r = 0; r < 4; ++r) {
      float s = l_st[mi][r];
      s += __shfl_xor(s, 1);
      s += __shfl_xor(s, 2);
      s += __shfl_xor(s, 4);
      s += __shfl_xor(s, 8);
      float inv = 1.0f / s;
      size_t rowoff = (size_t)(wv * 32 + mi * 16 + quad * 4 + r) * HIDDEN;
#pragma unroll
      for (int di = 0; di < 8; ++di)
        Ob[rowoff + di * 16 + lr] = (bf16_t)(oacc[mi][di][r] * inv);
    }
  }
}

extern "C" void kernel_launch(void* const* d_in, const int* in_sizes, int n_in,
                              void* d_out, int out_size, void* d_ws, size_t ws_size,
                              hipStream_t stream) {
  const float* x   = (const float*)d_in[0];
  const float* msk = (const float*)d_in[1];
  const float* Wq  = (const float*)d_in[2];
  const float* bq  = (const float*)d_in[3];
  const float* Wk  = (const float*)d_in[4];
  const float* bk  = (const float*)d_in[5];
  const float* Wv  = (const float*)d_in[6];
  const float* bv  = (const float*)d_in[7];
  const float* Wo  = (const float*)d_in[8];
  const float* bo  = (const float*)d_in[9];
  float* out = (float*)d_out;

  // workspace layout (bf16 elems), ~101 MB total
  bf16_t* Xb   = (bf16_t*)d_ws;
  bf16_t* Wqkb = Xb   + (size_t)MTOT * HIDDEN;            // Wq|Wk stacked [4096][2048]
  bf16_t* Wvb  = Wqkb + (size_t)2 * HIDDEN * HIDDEN;
  bf16_t* Wob  = Wvb  + (size_t)HIDDEN * HIDDEN;
  bf16_t* QKo  = Wob  + (size_t)HIDDEN * HIDDEN;          // [4096][4096]
  bf16_t* Vto  = QKo  + (size_t)MTOT * 2 * HIDDEN;        // [2048][4096]
  float*  bqk  = (float*)(Vto + (size_t)HIDDEN * MTOT);   // [4096] fp32
  bf16_t* Cb   = Xb;  // ctx aliases Xb (Xb dead after Vt GEMM)

  // fused casts: 6 regions x (HH/4 float4 / 256) blocks
  cvt_all<<<dim3(HIDDEN * HIDDEN / 4 / 256, 6), 256, 0, stream>>>(
      x, Wq, Wk, Wv, Wo, Xb, Wqkb, Wvb, Wob);
  pack_bias2<<<2 * HIDDEN / 256, 256, 0, stream>>>(bq, bk, bqk);

  // QK projection: [4096,2048] x [4096,2048]^T -> [4096][4096]
  gemm_bt<true, false><<<dim3(32, 32), 256, 0, stream>>>(Xb, Wqkb, bqk, QKo,
                                                         MTOT, 2 * HIDDEN, HIDDEN, 2 * HIDDEN);
  // V^T projection (operands swapped): [2048,2048] x [4096,2048]^T -> [2048][4096], row bias
  gemm_bt<true, true><<<dim3(32, 16), 256, 0, stream>>>(Wvb, Xb, bv, Vto,
                                                        HIDDEN, MTOT, HIDDEN, MTOT);
  // attention -> ctx bf16 [4096][2048]  (128-thread blocks, 4 blocks/CU)
  attn_kernel<<<dim3(SEQ / BQ, BATCH * NHEADS), 128, 0, stream>>>(QKo, Vto, msk, Cb);
  // output projection -> fp32 out
  gemm_bt<false, false><<<dim3(16, 32), 256, 0, stream>>>(Cb, Wob, bo, out,
                                                          MTOT, HIDDEN, HIDDEN, HIDDEN);
}